// Round 8
// baseline (789.177 us; speedup 1.0000x reference)
//
#include <hip/hip_runtime.h>
#include <hip/hip_fp16.h>
#include <math.h>

#define B_    128
#define NTOK  577
#define KSEL  172
#define M_WG  (B_*NTOK)    // 73856
#define M_SEL (B_*KSEL)    // 22016
#define DELTA 8e-3f        // uncertainty half-band for approx top-k

typedef float f32x4 __attribute__((ext_vector_type(4)));
typedef short s16x8 __attribute__((ext_vector_type(8)));
typedef short s16x4 __attribute__((ext_vector_type(4)));
typedef _Float16 f16x8 __attribute__((ext_vector_type(8)));

// async global->LDS 16B: per-lane global src; LDS dest is wave-uniform base + lane*16
__device__ __forceinline__ void gll16(const void* g, void* l) {
    __builtin_amdgcn_global_load_lds(
        (const __attribute__((address_space(1))) unsigned int*)g,
        (__attribute__((address_space(3))) unsigned int*)l, 16, 0, 0);
}

// ---- prep: F f32 -> f16 (one pass), zero scores + bn stats ----
__global__ __launch_bounds__(256) void prep_kernel(
    const float* __restrict__ F, short* __restrict__ Ff16,
    float* __restrict__ wsc, float* __restrict__ stats)
{
    const int gid = blockIdx.x * 256 + threadIdx.x;
    const int stride = gridDim.x * 256;
    const int n4 = M_WG * 512 / 4;
    for (int i = gid; i < n4; i += stride) {
        float4 v = *(const float4*)(F + (size_t)i * 4);
        short hs[4];
        hs[0] = (short)__half_as_ushort(__float2half(v.x));
        hs[1] = (short)__half_as_ushort(__float2half(v.y));
        hs[2] = (short)__half_as_ushort(__float2half(v.z));
        hs[3] = (short)__half_as_ushort(__float2half(v.w));
        *(s16x4*)(Ff16 + (size_t)i * 4) = *(s16x4*)hs;
    }
    if (gid < M_WG) wsc[gid] = 0.f;
    if (gid < 1024) stats[gid] = 0.f;
}

// ---- weight transpose -> f16 k-contiguous. BW packs [fc_w^T | mlp_w1^T] at k 0/512 ----
__global__ __launch_bounds__(256) void transpose_f16_kernel(
    const float* __restrict__ wgw1, const float* __restrict__ mw0,
    const float* __restrict__ mw1, const float* __restrict__ fcw,
    short* __restrict__ w1t, short* __restrict__ w0t, short* __restrict__ BW)
{
    const int z = blockIdx.z;
    const float* src; short* dst; int N, dstride, koff;
    if (z == 0)      { src = wgw1; dst = w1t; N = 512;  dstride = 512;  koff = 0; }
    else if (z == 1) { src = mw0;  dst = w0t; N = 512;  dstride = 512;  koff = 0; }
    else if (z == 2) { src = mw1;  dst = BW;  N = 1024; dstride = 1024; koff = 512; }
    else             { src = fcw;  dst = BW;  N = 1024; dstride = 1024; koff = 0; }
    const int n0 = blockIdx.x * 64;
    if (n0 >= N) return;
    const int k0 = blockIdx.y * 64;
    __shared__ float t[64][65];
    const int tid = threadIdx.x;
#pragma unroll
    for (int rr = 0; rr < 16; rr++) {
        int kl = rr * 4 + (tid >> 6), nl = tid & 63;
        t[kl][nl] = src[(size_t)(k0 + kl) * N + n0 + nl];
    }
    __syncthreads();
    const int nl = tid >> 2, kc = tid & 3;
    short hs[16];
#pragma unroll
    for (int j = 0; j < 16; j++)
        hs[j] = (short)__half_as_ushort(__float2half(t[kc * 16 + j][nl]));
    size_t o = (size_t)(n0 + nl) * dstride + koff + k0 + kc * 16;
    *(s16x8*)(dst + o)     = *(s16x8*)hs;
    *(s16x8*)(dst + o + 8) = *(s16x8*)(hs + 8);
}

// ---- shared 128x256 tile K-loop: PURE gll16 staging, 2 barriers, k-major LDS ----
// A LDS [kq(4)][128][8], B LDS [kq(4)][256][8]; 4 waves col-split; acc[8][4].
__device__ __forceinline__ void gemm_core(
    const short* __restrict__ Ag, int strideA, int rowbase,
    const short* __restrict__ Bg, int strideB, int nbase, int Ktot,
    int tid, short* Als, short* Bls, f32x4 acc[8][4])
{
    const int lane = tid & 63, wn = tid >> 6;
    const int r = lane & 15, kq = lane >> 4;
    for (int k0 = 0; k0 < Ktot; k0 += 32) {
#pragma unroll
        for (int p = 0; p < 2; p++) {
            int c = tid + p * 256, row = c & 127, kqs = c >> 7;
            gll16(Ag + (size_t)(rowbase + row) * strideA + k0 + kqs * 8, Als + c * 8);
        }
#pragma unroll
        for (int p = 0; p < 4; p++) {
            int c = tid + p * 256, col = c & 255, kqs = c >> 8;
            gll16(Bg + (size_t)(nbase + col) * strideB + k0 + kqs * 8, Bls + c * 8);
        }
        __syncthreads();
        f16x8 bf[4];
#pragma unroll
        for (int nf = 0; nf < 4; nf++)
            bf[nf] = *(const f16x8*)(Bls + kq * 2048 + (wn * 64 + nf * 16 + r) * 8);
#pragma unroll
        for (int mf = 0; mf < 8; mf++) {
            f16x8 a = *(const f16x8*)(Als + kq * 1024 + (mf * 16 + r) * 8);
#pragma unroll
            for (int nf = 0; nf < 4; nf++)
                acc[mf][nf] = __builtin_amdgcn_mfma_f32_16x16x32_f16(a, bf[nf], acc[mf][nf], 0, 0, 0);
        }
        __syncthreads();
    }
}

// ---- wg scores: s~[token] = sum_n relu((F@W1)[n]+b1[n])*v[n]  (f16 single-pass) ----
__global__ __launch_bounds__(256) void wg_f16_kernel(
    const short* __restrict__ Ff16, const short* __restrict__ W1t,
    const float* __restrict__ b1, const float* __restrict__ v,
    float* __restrict__ w_out)
{
    __shared__ short Als[4096], Bls[8192];
    const int tid = threadIdx.x, lane = tid & 63, wn = tid >> 6;
    const int r = lane & 15, kq = lane >> 4;
    const int rowbase = blockIdx.y * 128, nbase = blockIdx.x * 256;
    f32x4 acc[8][4];
#pragma unroll
    for (int i = 0; i < 8; i++)
#pragma unroll
        for (int j = 0; j < 4; j++) acc[i][j] = (f32x4)(0.0f);
    gemm_core(Ff16, 512, rowbase, W1t, 512, nbase, 512, tid, Als, Bls, acc);
    float b1v[4], vv[4];
#pragma unroll
    for (int nf = 0; nf < 4; nf++) {
        int col = nbase + wn * 64 + nf * 16 + r;
        b1v[nf] = b1[col]; vv[nf] = v[col];
    }
#pragma unroll
    for (int mf = 0; mf < 8; mf++)
#pragma unroll
        for (int i = 0; i < 4; i++) {
            float s = 0.f;
#pragma unroll
            for (int nf = 0; nf < 4; nf++)
                s += fmaxf(acc[mf][nf][i] + b1v[nf], 0.f) * vv[nf];
            s += __shfl_xor(s, 1); s += __shfl_xor(s, 2);
            s += __shfl_xor(s, 4); s += __shfl_xor(s, 8);
            if (r == 0)
                atomicAdd(&w_out[rowbase + mf * 16 + kq * 4 + i], s);
        }
}

// ---- topk on approx scores + certain/uncertain band classification ----
// If |s~-s| <= DELTA/2 everywhere, {s~>t~+DELTA} are truly in top-172, {s~<t~-DELTA}
// truly out; the band is decided by exact rescoring. Set-selection only (final sort asc).
__global__ __launch_bounds__(512) void topk2_kernel(
    const float* __restrict__ w, int* __restrict__ cin, int* __restrict__ unc,
    int* __restrict__ meta)
{
    __shared__ float sval[1024];
    __shared__ int   sidx[1024];
    __shared__ int mcnt, ucnt;
    __shared__ float thr_s;
    const int b = blockIdx.x;
    const int tid = threadIdx.x;
    for (int i = tid; i < 1024; i += 512) {
        if (i < 576) { sval[i] = w[b * NTOK + 1 + i]; sidx[i] = 1 + i; }
        else         { sval[i] = -1e38f;              sidx[i] = 0x7fffffff; }
    }
    __syncthreads();
    for (int ksz = 2; ksz <= 1024; ksz <<= 1) {
        for (int j = ksz >> 1; j > 0; j >>= 1) {
            int i = ((tid & ~(j - 1)) << 1) | (tid & (j - 1));
            int ixj = i | j;
            float va = sval[i], vb = sval[ixj];
            int ia = sidx[i], ib = sidx[ixj];
            bool a_first = (va > vb) || (va == vb && ia < ib);
            bool dirDesc = ((i & ksz) == 0);
            bool doswap = dirDesc ? (!a_first) : a_first;
            if (doswap) { sval[i] = vb; sval[ixj] = va; sidx[i] = ib; sidx[ixj] = ia; }
            __syncthreads();
        }
    }
    if (tid == 0) { thr_s = sval[KSEL - 1]; mcnt = 0; ucnt = 0; }
    __syncthreads();
    const float thr = thr_s;
    for (int i = tid; i < 576; i += 512) {
        float vv = sval[i]; int id = sidx[i];
        if (vv > thr + DELTA) {
            int p = atomicAdd(&mcnt, 1);
            cin[b * KSEL + p] = id;
        } else if (vv >= thr - DELTA) {
            int p = atomicAdd(&ucnt, 1);
            if (p < 256) unc[b * 256 + p] = id;
        }
    }
    __syncthreads();
    if (tid == 0) {
        int m = mcnt;
        int u = (ucnt < 256) ? ucnt : 256;
        meta[b * 4]     = m;
        meta[b * 4 + 1] = KSEL - m;
        meta[b * 4 + 2] = u;
    }
}

// ---- exact fp32 re-score of uncertain tokens (~5/batch) ----
__global__ __launch_bounds__(256) void refine_kernel(
    const float* __restrict__ F, const float* __restrict__ W1,
    const float* __restrict__ b1, const float* __restrict__ v,
    const int* __restrict__ unc, const int* __restrict__ meta,
    float* __restrict__ rscore)
{
    const int b = blockIdx.y, tid = threadIdx.x;
    const int u = meta[b * 4 + 2];
    __shared__ float fr[512];
    __shared__ float redbuf[4];
    for (int s = blockIdx.x; s < u; s += 32) {
        int tok = unc[b * 256 + s];
        __syncthreads();
        fr[tid]       = F[((size_t)b * NTOK + tok) * 512 + tid];
        fr[tid + 256] = F[((size_t)b * NTOK + tok) * 512 + tid + 256];
        __syncthreads();
        float a0 = b1[tid], a1 = b1[tid + 256];
#pragma unroll 4
        for (int k = 0; k < 512; k++) {
            float fk = fr[k];
            a0 = fmaf(fk, W1[(size_t)k * 512 + tid], a0);
            a1 = fmaf(fk, W1[(size_t)k * 512 + tid + 256], a1);
        }
        float p = fmaxf(a0, 0.f) * v[tid] + fmaxf(a1, 0.f) * v[tid + 256];
#pragma unroll
        for (int off = 32; off > 0; off >>= 1) p += __shfl_down(p, off);
        if ((tid & 63) == 0) redbuf[tid >> 6] = p;
        __syncthreads();
        if (tid == 0) rscore[b * 256 + s] = redbuf[0] + redbuf[1] + redbuf[2] + redbuf[3];
    }
}

// ---- final selection: certain + top-r uncertain by exact score; sort ascending ----
__global__ __launch_bounds__(256) void select_kernel(
    const int* __restrict__ cin, const int* __restrict__ unc,
    const float* __restrict__ rscore, const int* __restrict__ meta,
    int* __restrict__ idx_out)
{
    const int b = blockIdx.x, tid = threadIdx.x;
    const int m = meta[b * 4], u = meta[b * 4 + 2];
    __shared__ float uval[256];
    __shared__ int   uidx[256];
    __shared__ int   fin[256];
    if (tid < u) { uval[tid] = rscore[b * 256 + tid]; uidx[tid] = unc[b * 256 + tid]; }
    else         { uval[tid] = -1e38f;                uidx[tid] = 0x7fffffff; }
    __syncthreads();
    for (int ksz = 2; ksz <= 256; ksz <<= 1) {
        for (int j = ksz >> 1; j > 0; j >>= 1) {
            if (tid < 128) {
                int i = ((tid & ~(j - 1)) << 1) | (tid & (j - 1));
                int ixj = i | j;
                float va = uval[i], vb = uval[ixj];
                int ia = uidx[i], ib = uidx[ixj];
                bool a_first = (va > vb) || (va == vb && ia < ib);
                bool dirDesc = ((i & ksz) == 0);
                if (dirDesc ? !a_first : a_first) {
                    uval[i] = vb; uval[ixj] = va; uidx[i] = ib; uidx[ixj] = ia;
                }
            }
            __syncthreads();
        }
    }
    if (tid < m) fin[tid] = cin[b * KSEL + tid];
    else if (tid < KSEL) fin[tid] = uidx[tid - m];
    else fin[tid] = 0x7fffffff;
    __syncthreads();
    for (int ksz = 2; ksz <= 256; ksz <<= 1) {
        for (int j = ksz >> 1; j > 0; j >>= 1) {
            if (tid < 128) {
                int i = ((tid & ~(j - 1)) << 1) | (tid & (j - 1));
                int ixj = i | j;
                int a = fin[i], bb = fin[ixj];
                bool asc = ((i & ksz) == 0);
                if (asc ? (a > bb) : (a < bb)) { fin[i] = bb; fin[ixj] = a; }
            }
            __syncthreads();
        }
    }
    if (tid < KSEL) idx_out[b * KSEL + tid] = fin[tid];
}

// ---- gather + l2norm (exact f32) -> f16 into AY cols 0-511 ----
__global__ __launch_bounds__(128) void gather_norm_kernel(
    const float* __restrict__ F, const int* __restrict__ idx,
    short* __restrict__ AY)
{
    const int g = blockIdx.x;
    const int b = g / KSEL;
    const int tok = idx[g];
    const float4* src = (const float4*)(F + ((size_t)b * NTOK + tok) * 512);
    const int t = threadIdx.x;
    float4 v = src[t];
    float ss = v.x * v.x + v.y * v.y + v.z * v.z + v.w * v.w;
#pragma unroll
    for (int off = 32; off > 0; off >>= 1) ss += __shfl_down(ss, off);
    __shared__ float red[2];
    if ((t & 63) == 0) red[t >> 6] = ss;
    __syncthreads();
    float inv = 1.0f / (sqrtf(red[0] + red[1]) + 1e-8f);
    float xs[4] = {v.x * inv, v.y * inv, v.z * inv, v.w * inv};
    short hs[4];
#pragma unroll
    for (int j = 0; j < 4; j++) hs[j] = (short)__half_as_ushort(__float2half(xs[j]));
    *(s16x4*)(AY + (size_t)g * 1024 + t * 4) = *(s16x4*)hs;
}

// ---- x1 = f16(sel @ w0 + b0) -> AY cols 512-1023 (raw, pre-BN); fused stats ----
__global__ __launch_bounds__(256) void gemm_x1_kernel(
    short* __restrict__ AY, const short* __restrict__ W0t,
    const float* __restrict__ b0, float* __restrict__ stats)
{
    __shared__ short Als[4096], Bls[8192];
    const int tid = threadIdx.x, lane = tid & 63, wn = tid >> 6;
    const int r = lane & 15, kq = lane >> 4;
    const int rowbase = blockIdx.y * 128, nbase = blockIdx.x * 256;
    f32x4 acc[8][4];
#pragma unroll
    for (int i = 0; i < 8; i++)
#pragma unroll
        for (int j = 0; j < 4; j++) acc[i][j] = (f32x4)(0.0f);
    gemm_core(AY, 1024, rowbase, W0t, 512, nbase, 512, tid, Als, Bls, acc);
#pragma unroll
    for (int nf = 0; nf < 4; nf++) {
        int col = nbase + wn * 64 + nf * 16 + r;
        float b0v = b0[col];
        float cs = 0.f, cq = 0.f;
#pragma unroll
        for (int mf = 0; mf < 8; mf++)
#pragma unroll
            for (int i = 0; i < 4; i++) {
                int row = rowbase + mf * 16 + kq * 4 + i;
                float val = acc[mf][nf][i] + b0v;
                AY[(size_t)row * 1024 + 512 + col] = (short)__half_as_ushort(__float2half(val));
                cs += val; cq += val * val;
            }
        cs += __shfl_xor(cs, 16); cs += __shfl_xor(cs, 32);
        cq += __shfl_xor(cq, 16); cq += __shfl_xor(cq, 32);
        if (kq == 0) {
            atomicAdd(&stats[col], cs);
            atomicAdd(&stats[512 + col], cq);
        }
    }
}

__global__ void bn_finalize_kernel(const float* __restrict__ stats,
                                   const float* __restrict__ g,
                                   const float* __restrict__ b,
                                   float* __restrict__ ss)
{
    int c = threadIdx.x;  // 512
    float mean = stats[c] * (1.0f / M_SEL);
    float var = stats[512 + c] * (1.0f / M_SEL) - mean * mean;
    float sc = g[c] * rsqrtf(var + 1e-5f);
    ss[c] = sc;
    ss[512 + c] = b[c] - mean * sc;
}

// ---- BN affine + relu, in place on AY cols 512-1023 ----
__global__ __launch_bounds__(256) void bn_apply_kernel(
    short* __restrict__ AY, const float* __restrict__ ss)
{
    const int stride = gridDim.x * 256;
    const int ng = M_SEL * 512 / 8;
    for (int g = blockIdx.x * 256 + threadIdx.x; g < ng; g += stride) {
        int row = g >> 6, cg = g & 63;
        size_t o = (size_t)row * 1024 + 512 + cg * 8;
        s16x8 xv = *(const s16x8*)(AY + o);
        short hs[8];
#pragma unroll
        for (int j = 0; j < 8; j++) {
            int k = cg * 8 + j;
            float xf = __half2float(__ushort_as_half((unsigned short)xv[j]));
            float y = fmaxf(fmaf(xf, ss[k], ss[512 + k]), 0.f);
            hs[j] = (short)__half_as_ushort(__float2half(y));
        }
        *(s16x8*)(AY + o) = *(s16x8*)hs;
    }
}

// ---- out = [sel|y] @ [fc_w^T;w1^T] + f16(fcb) + b1   (single K=1024 GEMM) ----
__global__ __launch_bounds__(256) void gemm_out2_kernel(
    const short* __restrict__ AY, const short* __restrict__ BW,
    const float* __restrict__ fcb, const float* __restrict__ b1m,
    float* __restrict__ out)
{
    __shared__ short Als[4096], Bls[8192];
    const int tid = threadIdx.x, lane = tid & 63, wn = tid >> 6;
    const int r = lane & 15, kq = lane >> 4;
    const int rowbase = blockIdx.y * 128, nbase = blockIdx.x * 256;
    f32x4 acc[8][4];
#pragma unroll
    for (int i = 0; i < 8; i++)
#pragma unroll
        for (int j = 0; j < 4; j++) acc[i][j] = (f32x4)(0.0f);
    gemm_core(AY, 1024, rowbase, BW, 1024, nbase, 1024, tid, Als, Bls, acc);
#pragma unroll
    for (int nf = 0; nf < 4; nf++) {
        int col = nbase + wn * 64 + nf * 16 + r;
        float bb = __half2float(__float2half(fcb[col])) + b1m[col];
#pragma unroll
        for (int mf = 0; mf < 8; mf++)
#pragma unroll
            for (int i = 0; i < 4; i++) {
                int row = rowbase + mf * 16 + kq * 4 + i;
                out[(size_t)row * 1024 + col] = acc[mf][nf][i] + bb;
            }
    }
}

extern "C" void kernel_launch(void* const* d_in, const int* in_sizes, int n_in,
                              void* d_out, int out_size, void* d_ws, size_t ws_size,
                              hipStream_t stream)
{
    const float* features = (const float*)d_in[0];
    const float* wg_w1 = (const float*)d_in[2];
    const float* wg_b1 = (const float*)d_in[3];
    const float* wg_w2 = (const float*)d_in[4];
    const float* fc_w  = (const float*)d_in[6];
    const float* fc_b  = (const float*)d_in[7];
    const float* mlp_w0 = (const float*)d_in[8];
    const float* mlp_b0 = (const float*)d_in[9];
    const float* bn_g  = (const float*)d_in[10];
    const float* bn_b  = (const float*)d_in[11];
    const float* mlp_w1 = (const float*)d_in[12];
    const float* mlp_b1 = (const float*)d_in[13];
    float* out = (float*)d_out;

    char* ws = (char*)d_ws;
    float* w_scores  = (float*)(ws + 0);         // 73856 f32
    float* stats     = (float*)(ws + 295424);    // 1024 f32
    float* scaleshift= (float*)(ws + 299520);    // 1024 f32
    int*   meta      = (int*)  (ws + 303616);    // 512 i32
    int*   idx_sel   = (int*)  (ws + 305664);    // 22016 i32
    int*   cin_list  = (int*)  (ws + 393728);    // 22016 i32
    int*   unc_list  = (int*)  (ws + 481792);    // 32768 i32
    float* rscore    = (float*)(ws + 612864);    // 32768 f32
    short* w1t       = (short*)(ws + 743936);    // wg_w1^T f16 [512][512]
    short* w0t       = (short*)(ws + 1268224);   // mlp_w0^T f16 [512][512]
    short* BW        = (short*)(ws + 1792512);   // [fc_w^T|mlp_w1^T] f16 [1024][1024]
    short* Ff16      = (short*)(ws + 3889664);   // F f16 [73856][512]  (75.6 MB)
    short* AY        = (short*)(ws + 3889664);   // ALIAS: [22016][1024] (45.1 MB)
    // Ff16 is dead after wg_f16_kernel; AY written from gather onward. Total ~79.5 MB.

    prep_kernel<<<2048, 256, 0, stream>>>(features, Ff16, w_scores, stats);
    transpose_f16_kernel<<<dim3(16, 8, 4), 256, 0, stream>>>(
        wg_w1, mlp_w0, mlp_w1, fc_w, w1t, w0t, BW);
    wg_f16_kernel<<<dim3(2, 577), 256, 0, stream>>>(
        Ff16, w1t, wg_b1, wg_w2, w_scores);
    topk2_kernel<<<B_, 512, 0, stream>>>(w_scores, cin_list, unc_list, meta);
    refine_kernel<<<dim3(32, B_), 256, 0, stream>>>(
        features, wg_w1, wg_b1, wg_w2, unc_list, meta, rscore);
    select_kernel<<<B_, 256, 0, stream>>>(cin_list, unc_list, rscore, meta, idx_sel);
    gather_norm_kernel<<<M_SEL, 128, 0, stream>>>(features, idx_sel, AY);
    gemm_x1_kernel<<<dim3(2, 172), 256, 0, stream>>>(AY, w0t, mlp_b0, stats);
    bn_finalize_kernel<<<1, 512, 0, stream>>>(stats, bn_g, bn_b, scaleshift);
    bn_apply_kernel<<<1024, 256, 0, stream>>>(AY, scaleshift);
    gemm_out2_kernel<<<dim3(4, 172), 256, 0, stream>>>(
        AY, BW, fc_b, mlp_b1, out);
}